// Round 1
// baseline (498.608 us; speedup 1.0000x reference)
//
#include <hip/hip_runtime.h>
#include <hip/hip_bf16.h>
#include <cstdint>

using u16 = unsigned short;
typedef __attribute__((ext_vector_type(8))) short bf16x8;
typedef __attribute__((ext_vector_type(4))) float f32x4;
typedef __attribute__((ext_vector_type(4))) u16 u16x4;

#define MFMA_BF16(a, b, c) __builtin_amdgcn_mfma_f32_16x16x32_bf16((a), (b), (c), 0, 0, 0)

__device__ __forceinline__ u16 f2bf(float f) {
  __hip_bfloat16 h = __float2bfloat16(f);
  return __builtin_bit_cast(u16, h);
}

__device__ __forceinline__ void gl_lds16(const void* gsrc, void* ldst) {
  __builtin_amdgcn_global_load_lds(
      (__attribute__((address_space(1))) void*)const_cast<void*>(gsrc),
      (__attribute__((address_space(3))) void*)ldst, 16, 0, 0);
}

// ---------------------------------------------------------------- transpose+convert: src [K][N] f32 -> dst [N][K] bf16
__global__ __launch_bounds__(256) void transpose_conv(const float* __restrict__ src,
                                                      u16* __restrict__ dst, int K, int N) {
  __shared__ float t[32][33];
  const int bx = blockIdx.x, by = blockIdx.y;  // bx: N/32, by: K/32
  const int tid = threadIdx.x;
  const int r = tid >> 3, c = (tid & 7) * 4;
  const float4 v = *(const float4*)&src[(size_t)(by * 32 + r) * N + bx * 32 + c];
  t[r][c] = v.x; t[r][c + 1] = v.y; t[r][c + 2] = v.z; t[r][c + 3] = v.w;
  __syncthreads();
  u16x4 o;
  o.x = f2bf(t[c][r]); o.y = f2bf(t[c + 1][r]); o.z = f2bf(t[c + 2][r]); o.w = f2bf(t[c + 3][r]);
  *(u16x4*)&dst[(size_t)(bx * 32 + r) * K + by * 32 + c] = o;
}

// ---------------------------------------------------------------- V^T extraction: qkv [8192][3072] -> vt [128][64][1024]
__global__ __launch_bounds__(256) void transpose_v(const u16* __restrict__ qkv, u16* __restrict__ dst) {
  __shared__ u16 t[32][40];
  const int bx = blockIdx.x;  // d-block: 0..1
  const int by = blockIdx.y;  // n-block: 0..31
  const int bh = blockIdx.z;  // 0..127
  const int b = bh >> 4, h = bh & 15;
  const int tid = threadIdx.x;
  const int r = tid >> 3, c = (tid & 7) * 4;
  u16x4 v = *(const u16x4*)&qkv[(size_t)(b * 1024 + by * 32 + r) * 3072 + 2048 + h * 64 + bx * 32 + c];
  t[r][c] = v.x; t[r][c + 1] = v.y; t[r][c + 2] = v.z; t[r][c + 3] = v.w;
  __syncthreads();
  u16x4 o = {t[c][r], t[c + 1][r], t[c + 2][r], t[c + 3][r]};
  *(u16x4*)&dst[(size_t)bh * 65536 + (size_t)(bx * 32 + r) * 1024 + by * 32 + c] = o;
}

// ---------------------------------------------------------------- LayerNorm: x f32 [8192][1024] -> bf16 out
__global__ __launch_bounds__(256) void ln_kernel(const float* __restrict__ x, const float* __restrict__ g,
                                                 const float* __restrict__ b, u16* __restrict__ out) {
  const int row = blockIdx.x, tid = threadIdx.x;
  const float* xr = x + (size_t)row * 1024;
  float4 v = *(const float4*)&xr[tid * 4];
  float s = v.x + v.y + v.z + v.w;
  float s2 = v.x * v.x + v.y * v.y + v.z * v.z + v.w * v.w;
#pragma unroll
  for (int off = 32; off; off >>= 1) { s += __shfl_xor(s, off); s2 += __shfl_xor(s2, off); }
  __shared__ float ps[4], ps2[4];
  const int wave = tid >> 6;
  if ((tid & 63) == 0) { ps[wave] = s; ps2[wave] = s2; }
  __syncthreads();
  s = ps[0] + ps[1] + ps[2] + ps[3];
  s2 = ps2[0] + ps2[1] + ps2[2] + ps2[3];
  const float mu = s * (1.0f / 1024.0f);
  const float var = s2 * (1.0f / 1024.0f) - mu * mu;
  const float rs = rsqrtf(var + 1e-5f);
  float4 gv = *(const float4*)&g[tid * 4];
  float4 bv = *(const float4*)&b[tid * 4];
  u16x4 o;
  o.x = f2bf((v.x - mu) * rs * gv.x + bv.x);
  o.y = f2bf((v.y - mu) * rs * gv.y + bv.y);
  o.z = f2bf((v.z - mu) * rs * gv.z + bv.z);
  o.w = f2bf((v.w - mu) * rs * gv.w + bv.w);
  *(u16x4*)&out[(size_t)row * 1024 + tid * 4] = o;
}

// ---------------------------------------------------------------- GEMM: C[M][N] = A[M][K] * Bt[N][K]^T (+epilogue)
// EPI 0: bf16 out = acc + bias            (QKV)
// EPI 1: outf = xres + ls*(acc+bias)      (proj + residual1)
// EPI 2: bf16 out = gelu(acc+bias)        (FC1)
// EPI 3: outf += ls*(acc+bias)            (FC2 + residual2, RMW)
template <int EPI>
__global__ __launch_bounds__(256, 2) void gemm_bt(const u16* __restrict__ A, const u16* __restrict__ Bt,
                                                  const float* __restrict__ bias, const float* __restrict__ xres,
                                                  const float* __restrict__ ls, float* __restrict__ outf,
                                                  u16* __restrict__ outh, int M, int N, int K) {
  __shared__ __attribute__((aligned(16))) u16 As[128 * 32];
  __shared__ __attribute__((aligned(16))) u16 Bs[128 * 32];
  const int tid = threadIdx.x;
  const int wave = tid >> 6, lane = tid & 63;
  const int lrow = lane & 15, lhi = lane >> 4;
  const int bm = blockIdx.x, bn = blockIdx.y;
  const int wr = wave >> 1, wc = wave & 1;

  f32x4 zero = {0.f, 0.f, 0.f, 0.f};
  f32x4 acc[4][4];
#pragma unroll
  for (int i = 0; i < 4; i++)
#pragma unroll
    for (int j = 0; j < 4; j++) acc[i][j] = zero;

  const u16* Abase = A + (size_t)(bm * 128 + wave * 16 + (lane >> 2)) * K + (lane & 3) * 8;
  const u16* Bbase = Bt + (size_t)(bn * 128 + wave * 16 + (lane >> 2)) * K + (lane & 3) * 8;
  u16* AsW0 = &As[(wave * 16) * 32];
  u16* AsW1 = &As[(64 + wave * 16) * 32];
  u16* BsW0 = &Bs[(wave * 16) * 32];
  u16* BsW1 = &Bs[(64 + wave * 16) * 32];
  const size_t rowK64 = (size_t)64 * K;

  for (int kt = 0; kt < K; kt += 32) {
    __syncthreads();
    gl_lds16(Abase + kt, AsW0);
    gl_lds16(Abase + rowK64 + kt, AsW1);
    gl_lds16(Bbase + kt, BsW0);
    gl_lds16(Bbase + rowK64 + kt, BsW1);
    __syncthreads();
    bf16x8 af[4], bfr[4];
#pragma unroll
    for (int mi = 0; mi < 4; mi++) af[mi] = *(const bf16x8*)&As[(wr * 64 + mi * 16 + lrow) * 32 + lhi * 8];
#pragma unroll
    for (int ni = 0; ni < 4; ni++) bfr[ni] = *(const bf16x8*)&Bs[(wc * 64 + ni * 16 + lrow) * 32 + lhi * 8];
#pragma unroll
    for (int mi = 0; mi < 4; mi++)
#pragma unroll
      for (int ni = 0; ni < 4; ni++) acc[mi][ni] = MFMA_BF16(af[mi], bfr[ni], acc[mi][ni]);
  }

  const int row0 = bm * 128 + wr * 64;
  const int col0 = bn * 128 + wc * 64;
#pragma unroll
  for (int mi = 0; mi < 4; mi++) {
#pragma unroll
    for (int ni = 0; ni < 4; ni++) {
#pragma unroll
      for (int i = 0; i < 4; i++) {
        const int r = row0 + mi * 16 + lhi * 4 + i;
        const int c = col0 + ni * 16 + lrow;
        float v = acc[mi][ni][i];
        if constexpr (EPI == 0) {
          outh[(size_t)r * N + c] = f2bf(v + bias[c]);
        } else if constexpr (EPI == 1) {
          const size_t idx = (size_t)r * N + c;
          outf[idx] = xres[idx] + ls[c] * (v + bias[c]);
        } else if constexpr (EPI == 2) {
          v += bias[c];
          outh[(size_t)r * N + c] = f2bf(0.5f * v * (1.0f + erff(v * 0.70710678118654752f)));
        } else {
          const size_t idx = (size_t)r * N + c;
          outf[idx] += ls[c] * (v + bias[c]);
        }
      }
    }
  }
}

// ---------------------------------------------------------------- flash attention
// qkv: [8192][3072] bf16 (Q|K|V), vt: [128][64][1024] bf16, o: [8192][1024] bf16
__global__ __launch_bounds__(256, 2) void attn_kernel(const u16* __restrict__ qkv, const u16* __restrict__ vt,
                                                      u16* __restrict__ o) {
  __shared__ __attribute__((aligned(16))) u16 Qs[64 * 64];
  __shared__ __attribute__((aligned(16))) u16 Ks[128 * 64];
  __shared__ __attribute__((aligned(16))) u16 Vs[64 * 128];
  __shared__ __attribute__((aligned(16))) u16 Ps[4][16 * 128];
  const int tid = threadIdx.x;
  const int wave = tid >> 6, lane = tid & 63;
  const int lrow = lane & 15, lhi = lane >> 4;
  const int qt = blockIdx.x;  // 0..15
  const int bh = blockIdx.y;  // 0..127
  const int b = bh >> 4, h = bh & 15;

  // stage Q tile [64][64]
  {
    const u16* gq = qkv + (size_t)(b * 1024 + qt * 64 + wave * 8 + (lane >> 3)) * 3072 + h * 64 + (lane & 7) * 8;
    gl_lds16(gq, &Qs[(wave * 8) * 64]);
    gl_lds16(gq + (size_t)32 * 3072, &Qs[(32 + wave * 8) * 64]);
  }
  __syncthreads();
  bf16x8 qf0 = *(const bf16x8*)&Qs[(wave * 16 + lrow) * 64 + lhi * 8];
  bf16x8 qf1 = *(const bf16x8*)&Qs[(wave * 16 + lrow) * 64 + 32 + lhi * 8];

  float m_[4], l_[4];
  f32x4 oa[4];
  f32x4 zero = {0.f, 0.f, 0.f, 0.f};
#pragma unroll
  for (int i = 0; i < 4; i++) { m_[i] = -1e30f; l_[i] = 0.f; oa[i] = zero; }

  const u16* kg = qkv + (size_t)(b * 1024 + wave * 8 + (lane >> 3)) * 3072 + 1024 + h * 64 + (lane & 7) * 8;
  const u16* vg = vt + (size_t)bh * 65536 + (size_t)(wave * 4 + (lane >> 4)) * 1024 + (lane & 15) * 8;

  for (int kt = 0; kt < 1024; kt += 128) {
    __syncthreads();
#pragma unroll
    for (int i = 0; i < 4; i++) gl_lds16(kg + (size_t)(kt + i * 32) * 3072, &Ks[(i * 32 + wave * 8) * 64]);
#pragma unroll
    for (int i = 0; i < 4; i++) gl_lds16(vg + (size_t)(i * 16) * 1024 + kt, &Vs[(i * 16 + wave * 4) * 128]);
    __syncthreads();

    // S = Q K^T  (rows: wave's 16 q-rows, cols: 128 kv)
    f32x4 sf[8];
#pragma unroll
    for (int n = 0; n < 8; n++) sf[n] = zero;
#pragma unroll
    for (int n = 0; n < 8; n++) {
      bf16x8 kf0 = *(const bf16x8*)&Ks[(n * 16 + lrow) * 64 + lhi * 8];
      bf16x8 kf1 = *(const bf16x8*)&Ks[(n * 16 + lrow) * 64 + 32 + lhi * 8];
      sf[n] = MFMA_BF16(qf0, kf0, sf[n]);
      sf[n] = MFMA_BF16(qf1, kf1, sf[n]);
    }

    // online softmax (row = lhi*4+i across 16 lanes)
    float tm[4] = {-1e30f, -1e30f, -1e30f, -1e30f};
#pragma unroll
    for (int n = 0; n < 8; n++)
#pragma unroll
      for (int i = 0; i < 4; i++) tm[i] = fmaxf(tm[i], sf[n][i]);
#pragma unroll
    for (int i = 0; i < 4; i++) tm[i] *= 0.125f;
#pragma unroll
    for (int off = 1; off < 16; off <<= 1)
#pragma unroll
      for (int i = 0; i < 4; i++) tm[i] = fmaxf(tm[i], __shfl_xor(tm[i], off));
    float al[4];
#pragma unroll
    for (int i = 0; i < 4; i++) {
      const float mn = fmaxf(m_[i], tm[i]);
      al[i] = __expf(m_[i] - mn);
      m_[i] = mn;
    }
    float rs[4] = {0.f, 0.f, 0.f, 0.f};
#pragma unroll
    for (int n = 0; n < 8; n++)
#pragma unroll
      for (int i = 0; i < 4; i++) {
        const float p = __expf(sf[n][i] * 0.125f - m_[i]);
        rs[i] += p;
        Ps[wave][(lhi * 4 + i) * 128 + n * 16 + lrow] = f2bf(p);
      }
#pragma unroll
    for (int off = 1; off < 16; off <<= 1)
#pragma unroll
      for (int i = 0; i < 4; i++) rs[i] += __shfl_xor(rs[i], off);
#pragma unroll
    for (int i = 0; i < 4; i++) l_[i] = l_[i] * al[i] + rs[i];
#pragma unroll
    for (int n2 = 0; n2 < 4; n2++)
#pragma unroll
      for (int i = 0; i < 4; i++) oa[n2][i] *= al[i];

    // O += P V   (P: [16][128] from LDS, V^T: [64][128] in LDS)
#pragma unroll
    for (int ks = 0; ks < 4; ks++) {
      bf16x8 pf = *(const bf16x8*)&Ps[wave][lrow * 128 + ks * 32 + lhi * 8];
#pragma unroll
      for (int n2 = 0; n2 < 4; n2++) {
        bf16x8 vf = *(const bf16x8*)&Vs[(n2 * 16 + lrow) * 128 + ks * 32 + lhi * 8];
        oa[n2] = MFMA_BF16(pf, vf, oa[n2]);
      }
    }
  }

#pragma unroll
  for (int n2 = 0; n2 < 4; n2++)
#pragma unroll
    for (int i = 0; i < 4; i++) {
      const int tok = qt * 64 + wave * 16 + lhi * 4 + i;
      o[(size_t)(b * 1024 + tok) * 1024 + h * 64 + n2 * 16 + lrow] = f2bf(oa[n2][i] / l_[i]);
    }
}

// ----------------------------------------------------------------
extern "C" void kernel_launch(void* const* d_in, const int* in_sizes, int n_in, void* d_out, int out_size,
                              void* d_ws, size_t ws_size, hipStream_t stream) {
  const float* x = (const float*)d_in[0];
  const float* ln1_g = (const float*)d_in[1];
  const float* ln1_b = (const float*)d_in[2];
  const float* qkv_w = (const float*)d_in[3];
  const float* qkv_b = (const float*)d_in[4];
  const float* proj_w = (const float*)d_in[5];
  const float* proj_b = (const float*)d_in[6];
  const float* ls1_g = (const float*)d_in[7];
  const float* ln2_g = (const float*)d_in[8];
  const float* ln2_b = (const float*)d_in[9];
  const float* fc1_w = (const float*)d_in[10];
  const float* fc1_b = (const float*)d_in[11];
  const float* fc2_w = (const float*)d_in[12];
  const float* fc2_b = (const float*)d_in[13];
  const float* ls2_g = (const float*)d_in[14];
  float* out = (float*)d_out;

  u16* w = (u16*)d_ws;
  u16* wq = w;                          // [3072][1024]
  u16* wp = wq + (size_t)3072 * 1024;   // [1024][1024]
  u16* wf1 = wp + (size_t)1024 * 1024;  // [4096][1024]
  u16* wf2 = wf1 + (size_t)4096 * 1024; // [1024][4096]
  u16* hbuf = wf2 + (size_t)1024 * 4096;  // [8192][1024]
  u16* qkvb = hbuf + (size_t)8192 * 1024; // [8192][3072]
  u16* vtb = qkvb + (size_t)8192 * 3072;  // [128][64][1024]
  u16* ob = vtb + (size_t)128 * 64 * 1024; // [8192][1024]
  u16* hid = qkvb;  // [8192][4096] aliases qkv+vtb (both dead by FC1)

  // weight transposes (fp32 -> bf16, [K][N] -> [N][K])
  transpose_conv<<<dim3(96, 32), 256, 0, stream>>>(qkv_w, wq, 1024, 3072);
  transpose_conv<<<dim3(32, 32), 256, 0, stream>>>(proj_w, wp, 1024, 1024);
  transpose_conv<<<dim3(128, 32), 256, 0, stream>>>(fc1_w, wf1, 1024, 4096);
  transpose_conv<<<dim3(32, 128), 256, 0, stream>>>(fc2_w, wf2, 4096, 1024);

  // LN1
  ln_kernel<<<8192, 256, 0, stream>>>(x, ln1_g, ln1_b, hbuf);
  // QKV
  gemm_bt<0><<<dim3(64, 24), 256, 0, stream>>>(hbuf, wq, qkv_b, nullptr, nullptr, nullptr, qkvb, 8192, 3072, 1024);
  // V^T extraction
  transpose_v<<<dim3(2, 32, 128), 256, 0, stream>>>(qkvb, vtb);
  // attention
  attn_kernel<<<dim3(16, 128), 256, 0, stream>>>(qkvb, vtb, ob);
  // proj + residual1 -> d_out (fp32 x2)
  gemm_bt<1><<<dim3(64, 8), 256, 0, stream>>>(ob, wp, proj_b, x, ls1_g, out, nullptr, 8192, 1024, 1024);
  // LN2
  ln_kernel<<<8192, 256, 0, stream>>>(out, ln2_g, ln2_b, hbuf);
  // FC1 + GELU
  gemm_bt<2><<<dim3(64, 32), 256, 0, stream>>>(hbuf, wf1, fc1_b, nullptr, nullptr, nullptr, hid, 8192, 4096, 1024);
  // FC2 + residual2 (RMW on d_out)
  gemm_bt<3><<<dim3(64, 8), 256, 0, stream>>>(hid, wf2, fc2_b, nullptr, ls2_g, out, nullptr, 8192, 1024, 4096);
}

// Round 2
// 426.983 us; speedup vs baseline: 1.1677x; 1.1677x over previous
//
#include <hip/hip_runtime.h>
#include <hip/hip_bf16.h>
#include <cstdint>

using u16 = unsigned short;
typedef __attribute__((ext_vector_type(8))) short bf16x8;
typedef __attribute__((ext_vector_type(4))) float f32x4;
typedef __attribute__((ext_vector_type(4))) u16 u16x4;

#define MFMA_BF16(a, b, c) __builtin_amdgcn_mfma_f32_16x16x32_bf16((a), (b), (c), 0, 0, 0)

__device__ __forceinline__ u16 f2bf(float f) {
  __hip_bfloat16 h = __float2bfloat16(f);
  return __builtin_bit_cast(u16, h);
}

__device__ __forceinline__ void gl_lds16(const void* gsrc, void* ldst) {
  __builtin_amdgcn_global_load_lds(
      (__attribute__((address_space(1))) void*)const_cast<void*>(gsrc),
      (__attribute__((address_space(3))) void*)ldst, 16, 0, 0);
}

// ---------------------------------------------------------------- transpose+convert: src [K][N] f32 -> dst [N][K] bf16
__global__ __launch_bounds__(256) void transpose_conv(const float* __restrict__ src,
                                                      u16* __restrict__ dst, int K, int N) {
  __shared__ float t[32][33];
  const int bx = blockIdx.x, by = blockIdx.y;  // bx: N/32, by: K/32
  const int tid = threadIdx.x;
  const int r = tid >> 3, c = (tid & 7) * 4;
  const float4 v = *(const float4*)&src[(size_t)(by * 32 + r) * N + bx * 32 + c];
  t[r][c] = v.x; t[r][c + 1] = v.y; t[r][c + 2] = v.z; t[r][c + 3] = v.w;
  __syncthreads();
  u16x4 o;
  o.x = f2bf(t[c][r]); o.y = f2bf(t[c + 1][r]); o.z = f2bf(t[c + 2][r]); o.w = f2bf(t[c + 3][r]);
  *(u16x4*)&dst[(size_t)(bx * 32 + r) * K + by * 32 + c] = o;
}

// ---------------------------------------------------------------- V^T extraction: qkv [8192][3072] -> vt [128][64][1024]
__global__ __launch_bounds__(256) void transpose_v(const u16* __restrict__ qkv, u16* __restrict__ dst) {
  __shared__ u16 t[32][40];
  const int bx = blockIdx.x;  // d-block: 0..1
  const int by = blockIdx.y;  // n-block: 0..31
  const int bh = blockIdx.z;  // 0..127
  const int b = bh >> 4, h = bh & 15;
  const int tid = threadIdx.x;
  const int r = tid >> 3, c = (tid & 7) * 4;
  u16x4 v = *(const u16x4*)&qkv[(size_t)(b * 1024 + by * 32 + r) * 3072 + 2048 + h * 64 + bx * 32 + c];
  t[r][c] = v.x; t[r][c + 1] = v.y; t[r][c + 2] = v.z; t[r][c + 3] = v.w;
  __syncthreads();
  u16x4 o = {t[c][r], t[c + 1][r], t[c + 2][r], t[c + 3][r]};
  *(u16x4*)&dst[(size_t)bh * 65536 + (size_t)(bx * 32 + r) * 1024 + by * 32 + c] = o;
}

// ---------------------------------------------------------------- LayerNorm: x f32 [8192][1024] -> bf16 out
__global__ __launch_bounds__(256) void ln_kernel(const float* __restrict__ x, const float* __restrict__ g,
                                                 const float* __restrict__ b, u16* __restrict__ out) {
  const int row = blockIdx.x, tid = threadIdx.x;
  const float* xr = x + (size_t)row * 1024;
  float4 v = *(const float4*)&xr[tid * 4];
  float s = v.x + v.y + v.z + v.w;
  float s2 = v.x * v.x + v.y * v.y + v.z * v.z + v.w * v.w;
#pragma unroll
  for (int off = 32; off; off >>= 1) { s += __shfl_xor(s, off); s2 += __shfl_xor(s2, off); }
  __shared__ float ps[4], ps2[4];
  const int wave = tid >> 6;
  if ((tid & 63) == 0) { ps[wave] = s; ps2[wave] = s2; }
  __syncthreads();
  s = ps[0] + ps[1] + ps[2] + ps[3];
  s2 = ps2[0] + ps2[1] + ps2[2] + ps2[3];
  const float mu = s * (1.0f / 1024.0f);
  const float var = s2 * (1.0f / 1024.0f) - mu * mu;
  const float rs = rsqrtf(var + 1e-5f);
  float4 gv = *(const float4*)&g[tid * 4];
  float4 bv = *(const float4*)&b[tid * 4];
  u16x4 o;
  o.x = f2bf((v.x - mu) * rs * gv.x + bv.x);
  o.y = f2bf((v.y - mu) * rs * gv.y + bv.y);
  o.z = f2bf((v.z - mu) * rs * gv.z + bv.z);
  o.w = f2bf((v.w - mu) * rs * gv.w + bv.w);
  *(u16x4*)&out[(size_t)row * 1024 + tid * 4] = o;
}

// ---------------------------------------------------------------- GEMM: C[M][N] = A[M][K] * Bt[N][K]^T (+epilogue)
// EPI 0: bf16 out = acc + bias            (QKV)
// EPI 1: outf = xres + ls*(acc+bias)      (proj + residual1)
// EPI 2: bf16 out = gelu(acc+bias)        (FC1)
// EPI 3: outf += ls*(acc+bias)            (FC2 + residual2, RMW)
template <int EPI>
__global__ __launch_bounds__(256, 2) void gemm_bt(const u16* __restrict__ A, const u16* __restrict__ Bt,
                                                  const float* __restrict__ bias, const float* __restrict__ xres,
                                                  const float* __restrict__ ls, float* __restrict__ outf,
                                                  u16* __restrict__ outh, int M, int N, int K) {
  __shared__ __attribute__((aligned(16))) u16 As[128 * 32];
  __shared__ __attribute__((aligned(16))) u16 Bs[128 * 32];
  const int tid = threadIdx.x;
  const int wave = tid >> 6, lane = tid & 63;
  const int lrow = lane & 15, lhi = lane >> 4;
  const int bm = blockIdx.x, bn = blockIdx.y;
  const int wr = wave >> 1, wc = wave & 1;

  f32x4 zero = {0.f, 0.f, 0.f, 0.f};
  f32x4 acc[4][4];
#pragma unroll
  for (int i = 0; i < 4; i++)
#pragma unroll
    for (int j = 0; j < 4; j++) acc[i][j] = zero;

  const u16* Abase = A + (size_t)(bm * 128 + wave * 16 + (lane >> 2)) * K + (lane & 3) * 8;
  const u16* Bbase = Bt + (size_t)(bn * 128 + wave * 16 + (lane >> 2)) * K + (lane & 3) * 8;
  u16* AsW0 = &As[(wave * 16) * 32];
  u16* AsW1 = &As[(64 + wave * 16) * 32];
  u16* BsW0 = &Bs[(wave * 16) * 32];
  u16* BsW1 = &Bs[(64 + wave * 16) * 32];
  const size_t rowK64 = (size_t)64 * K;

  for (int kt = 0; kt < K; kt += 32) {
    __syncthreads();
    gl_lds16(Abase + kt, AsW0);
    gl_lds16(Abase + rowK64 + kt, AsW1);
    gl_lds16(Bbase + kt, BsW0);
    gl_lds16(Bbase + rowK64 + kt, BsW1);
    __syncthreads();
    bf16x8 af[4], bfr[4];
#pragma unroll
    for (int mi = 0; mi < 4; mi++) af[mi] = *(const bf16x8*)&As[(wr * 64 + mi * 16 + lrow) * 32 + lhi * 8];
#pragma unroll
    for (int ni = 0; ni < 4; ni++) bfr[ni] = *(const bf16x8*)&Bs[(wc * 64 + ni * 16 + lrow) * 32 + lhi * 8];
#pragma unroll
    for (int mi = 0; mi < 4; mi++)
#pragma unroll
      for (int ni = 0; ni < 4; ni++) acc[mi][ni] = MFMA_BF16(af[mi], bfr[ni], acc[mi][ni]);
  }

  const int row0 = bm * 128 + wr * 64;
  const int col0 = bn * 128 + wc * 64;
#pragma unroll
  for (int mi = 0; mi < 4; mi++) {
#pragma unroll
    for (int ni = 0; ni < 4; ni++) {
#pragma unroll
      for (int i = 0; i < 4; i++) {
        const int r = row0 + mi * 16 + lhi * 4 + i;
        const int c = col0 + ni * 16 + lrow;
        float v = acc[mi][ni][i];
        if constexpr (EPI == 0) {
          outh[(size_t)r * N + c] = f2bf(v + bias[c]);
        } else if constexpr (EPI == 1) {
          const size_t idx = (size_t)r * N + c;
          outf[idx] = xres[idx] + ls[c] * (v + bias[c]);
        } else if constexpr (EPI == 2) {
          v += bias[c];
          outh[(size_t)r * N + c] = f2bf(0.5f * v * (1.0f + erff(v * 0.70710678118654752f)));
        } else {
          const size_t idx = (size_t)r * N + c;
          outf[idx] += ls[c] * (v + bias[c]);
        }
      }
    }
  }
}

// ---------------------------------------------------------------- flash attention (T2-swizzled LDS)
// qkv: [8192][3072] bf16 (Q|K|V), vt: [128][64][1024] bf16, o: [8192][1024] bf16
// LDS tiles XOR-swizzled at 16B-chunk granularity; staging via global_load_lds
// keeps the LDS destination LINEAR and applies the inverse permutation to the
// per-lane GLOBAL source chunk (rule #21 / m173 pattern).
__global__ __launch_bounds__(256, 3) void attn_kernel(const u16* __restrict__ qkv, const u16* __restrict__ vt,
                                                      u16* __restrict__ o) {
  __shared__ __attribute__((aligned(16))) u16 Ks[128 * 64];      // [k=128][d=64], 8 chunks/row, phys = log ^ (row&7)
  __shared__ __attribute__((aligned(16))) u16 Vs[64 * 128];      // [d=64][kv=128], 16 chunks/row, phys = log ^ (row&15)
  __shared__ __attribute__((aligned(16))) u16 PQ[4 * 16 * 128];  // Ps per wave [q=16][kv=128]; first 8KB = Qs
  u16* Qs = PQ;  // [64][64], same swizzle as Ks; dead after prologue
  const int tid = threadIdx.x;
  const int wave = tid >> 6, lane = tid & 63;
  const int lrow = lane & 15, lhi = lane >> 4;
  const int qt = blockIdx.x;  // 0..15
  const int bh = blockIdx.y;  // 0..127
  const int b = bh >> 4, h = bh & 15;
  // inverse-swizzle source chunk indices for staging (lane-constant)
  const int swz8 = (lane & 7) ^ (lane >> 3);                   // 8-chunk rows (K/Q): row&7 == lane>>3 at stage
  const int swz16 = (lane & 15) ^ (wave * 4 + (lane >> 4));    // 16-chunk rows (V): row&15 == wave*4 + lane>>4

  // stage Q tile [64][64] (swizzled)
  {
    const u16* gq = qkv + (size_t)(b * 1024 + qt * 64 + wave * 8 + (lane >> 3)) * 3072 + h * 64 + swz8 * 8;
    gl_lds16(gq, &Qs[(wave * 8) * 64]);
    gl_lds16(gq + (size_t)32 * 3072, &Qs[(32 + wave * 8) * 64]);
  }
  __syncthreads();
  const int pq0 = (lhi ^ (lrow & 7)) * 8;  // phys element offset of logical chunk lhi, rows with row&7==lrow&7
  bf16x8 qf0 = *(const bf16x8*)&Qs[(wave * 16 + lrow) * 64 + pq0];
  bf16x8 qf1 = *(const bf16x8*)&Qs[(wave * 16 + lrow) * 64 + (pq0 ^ 32)];

  float m_[4], l_[4];
  f32x4 oa[4];
  f32x4 zero = {0.f, 0.f, 0.f, 0.f};
#pragma unroll
  for (int i = 0; i < 4; i++) { m_[i] = -1e30f; l_[i] = 0.f; oa[i] = zero; }

  const u16* kg = qkv + (size_t)(b * 1024 + wave * 8 + (lane >> 3)) * 3072 + 1024 + h * 64 + swz8 * 8;
  const u16* vg = vt + (size_t)bh * 65536 + (size_t)(wave * 4 + (lane >> 4)) * 1024 + swz16 * 8;

  for (int kt = 0; kt < 1024; kt += 128) {
    __syncthreads();
#pragma unroll
    for (int i = 0; i < 4; i++) gl_lds16(kg + (size_t)(kt + i * 32) * 3072, &Ks[(i * 32 + wave * 8) * 64]);
#pragma unroll
    for (int i = 0; i < 4; i++) gl_lds16(vg + (size_t)(i * 16) * 1024 + kt, &Vs[(i * 16 + wave * 4) * 128]);
    __syncthreads();

    // S = Q K^T  (rows: wave's 16 q-rows, cols: 128 kv)
    f32x4 sf[8];
#pragma unroll
    for (int n = 0; n < 8; n++) sf[n] = zero;
#pragma unroll
    for (int n = 0; n < 8; n++) {
      bf16x8 kf0 = *(const bf16x8*)&Ks[(n * 16 + lrow) * 64 + pq0];
      bf16x8 kf1 = *(const bf16x8*)&Ks[(n * 16 + lrow) * 64 + (pq0 ^ 32)];
      sf[n] = MFMA_BF16(qf0, kf0, sf[n]);
      sf[n] = MFMA_BF16(qf1, kf1, sf[n]);
    }

    // online softmax (row = lhi*4+i across 16 lanes)
    float tm[4] = {-1e30f, -1e30f, -1e30f, -1e30f};
#pragma unroll
    for (int n = 0; n < 8; n++)
#pragma unroll
      for (int i = 0; i < 4; i++) tm[i] = fmaxf(tm[i], sf[n][i]);
#pragma unroll
    for (int i = 0; i < 4; i++) tm[i] *= 0.125f;
#pragma unroll
    for (int off = 1; off < 16; off <<= 1)
#pragma unroll
      for (int i = 0; i < 4; i++) tm[i] = fmaxf(tm[i], __shfl_xor(tm[i], off));
    float al[4];
#pragma unroll
    for (int i = 0; i < 4; i++) {
      const float mn = fmaxf(m_[i], tm[i]);
      al[i] = __expf(m_[i] - mn);
      m_[i] = mn;
    }
    float rs[4] = {0.f, 0.f, 0.f, 0.f};
#pragma unroll
    for (int n = 0; n < 8; n++)
#pragma unroll
      for (int i = 0; i < 4; i++) {
        const float p = __expf(sf[n][i] * 0.125f - m_[i]);
        rs[i] += p;
        // logical [q = lhi*4+i][col = n*16+lrow]; phys chunk = (n*2 + (lrow>>3)) ^ q
        const int q = lhi * 4 + i;
        PQ[wave * 2048 + q * 128 + (((n * 2 + (lrow >> 3)) ^ q) * 8) + (lrow & 7)] = f2bf(p);
      }
#pragma unroll
    for (int off = 1; off < 16; off <<= 1)
#pragma unroll
      for (int i = 0; i < 4; i++) rs[i] += __shfl_xor(rs[i], off);
#pragma unroll
    for (int i = 0; i < 4; i++) l_[i] = l_[i] * al[i] + rs[i];
#pragma unroll
    for (int n2 = 0; n2 < 4; n2++)
#pragma unroll
      for (int i = 0; i < 4; i++) oa[n2][i] *= al[i];

    // O += P V   (P: [16][128] swizzled LDS, V^T: [64][128] swizzled LDS)
#pragma unroll
    for (int ks = 0; ks < 4; ks++) {
      bf16x8 pf = *(const bf16x8*)&PQ[wave * 2048 + lrow * 128 + (((ks * 4 + lhi) ^ lrow) * 8)];
#pragma unroll
      for (int n2 = 0; n2 < 4; n2++) {
        bf16x8 vf = *(const bf16x8*)&Vs[(n2 * 16 + lrow) * 128 + (((ks * 4 + lhi) ^ lrow) * 8)];
        oa[n2] = MFMA_BF16(pf, vf, oa[n2]);
      }
    }
  }

#pragma unroll
  for (int n2 = 0; n2 < 4; n2++)
#pragma unroll
    for (int i = 0; i < 4; i++) {
      const int tok = qt * 64 + wave * 16 + lhi * 4 + i;
      o[(size_t)(b * 1024 + tok) * 1024 + h * 64 + n2 * 16 + lrow] = f2bf(oa[n2][i] / l_[i]);
    }
}

// ----------------------------------------------------------------
extern "C" void kernel_launch(void* const* d_in, const int* in_sizes, int n_in, void* d_out, int out_size,
                              void* d_ws, size_t ws_size, hipStream_t stream) {
  const float* x = (const float*)d_in[0];
  const float* ln1_g = (const float*)d_in[1];
  const float* ln1_b = (const float*)d_in[2];
  const float* qkv_w = (const float*)d_in[3];
  const float* qkv_b = (const float*)d_in[4];
  const float* proj_w = (const float*)d_in[5];
  const float* proj_b = (const float*)d_in[6];
  const float* ls1_g = (const float*)d_in[7];
  const float* ln2_g = (const float*)d_in[8];
  const float* ln2_b = (const float*)d_in[9];
  const float* fc1_w = (const float*)d_in[10];
  const float* fc1_b = (const float*)d_in[11];
  const float* fc2_w = (const float*)d_in[12];
  const float* fc2_b = (const float*)d_in[13];
  const float* ls2_g = (const float*)d_in[14];
  float* out = (float*)d_out;

  u16* w = (u16*)d_ws;
  u16* wq = w;                          // [3072][1024]
  u16* wp = wq + (size_t)3072 * 1024;   // [1024][1024]
  u16* wf1 = wp + (size_t)1024 * 1024;  // [4096][1024]
  u16* wf2 = wf1 + (size_t)4096 * 1024; // [1024][4096]
  u16* hbuf = wf2 + (size_t)1024 * 4096;  // [8192][1024]
  u16* qkvb = hbuf + (size_t)8192 * 1024; // [8192][3072]
  u16* vtb = qkvb + (size_t)8192 * 3072;  // [128][64][1024]
  u16* ob = vtb + (size_t)128 * 64 * 1024; // [8192][1024]
  u16* hid = qkvb;  // [8192][4096] aliases qkv+vtb (both dead by FC1)

  // weight transposes (fp32 -> bf16, [K][N] -> [N][K])
  transpose_conv<<<dim3(96, 32), 256, 0, stream>>>(qkv_w, wq, 1024, 3072);
  transpose_conv<<<dim3(32, 32), 256, 0, stream>>>(proj_w, wp, 1024, 1024);
  transpose_conv<<<dim3(128, 32), 256, 0, stream>>>(fc1_w, wf1, 1024, 4096);
  transpose_conv<<<dim3(32, 128), 256, 0, stream>>>(fc2_w, wf2, 4096, 1024);

  // LN1
  ln_kernel<<<8192, 256, 0, stream>>>(x, ln1_g, ln1_b, hbuf);
  // QKV
  gemm_bt<0><<<dim3(64, 24), 256, 0, stream>>>(hbuf, wq, qkv_b, nullptr, nullptr, nullptr, qkvb, 8192, 3072, 1024);
  // V^T extraction
  transpose_v<<<dim3(2, 32, 128), 256, 0, stream>>>(qkvb, vtb);
  // attention
  attn_kernel<<<dim3(16, 128), 256, 0, stream>>>(qkvb, vtb, ob);
  // proj + residual1 -> d_out (fp32 x2)
  gemm_bt<1><<<dim3(64, 8), 256, 0, stream>>>(ob, wp, proj_b, x, ls1_g, out, nullptr, 8192, 1024, 1024);
  // LN2
  ln_kernel<<<8192, 256, 0, stream>>>(out, ln2_g, ln2_b, hbuf);
  // FC1 + GELU
  gemm_bt<2><<<dim3(64, 32), 256, 0, stream>>>(hbuf, wf1, fc1_b, nullptr, nullptr, nullptr, hid, 8192, 4096, 1024);
  // FC2 + residual2 (RMW on d_out)
  gemm_bt<3><<<dim3(64, 8), 256, 0, stream>>>(hid, wf2, fc2_b, nullptr, ls2_g, out, nullptr, 8192, 1024, 4096);
}